// Round 12
// baseline (204.386 us; speedup 1.0000x reference)
//
#include <hip/hip_runtime.h>
#include <hip/hip_bf16.h>
#include <hip/hip_fp16.h>
#include <type_traits>

#define NG 64          // number of graphs
#define FLAT 2904      // FC output width
#define K128 128       // inner dim for both GEMMs
#define BKB 256        // cols per bucket (col >> 8)

typedef _Float16 h4 __attribute__((ext_vector_type(4)));     // 8B
typedef _Float16 half8 __attribute__((ext_vector_type(8)));  // 16B MFMA frag
typedef float f32x4 __attribute__((ext_vector_type(4)));

// ---------------------------------------------------------------- utilities
__device__ __forceinline__ float4 ld4(const float* p) { return *(const float4*)p; }
__device__ __forceinline__ float4 ldh4(const _Float16* p) {
    h4 h = *(const h4*)p;
    return make_float4((float)h.x, (float)h.y, (float)h.z, (float)h.w);
}
__device__ __forceinline__ void sth4(_Float16* p, float4 v) {
    h4 h; h.x = (_Float16)v.x; h.y = (_Float16)v.y; h.z = (_Float16)v.z; h.w = (_Float16)v.w;
    *(h4*)p = h;
}
__device__ __forceinline__ float unpack_w(unsigned q) {
    return (float)__builtin_bit_cast(_Float16, (unsigned short)(q & 0xFFFFu));
}

// ------------------------------------------------- init: zero accum + both W converts
__global__ __launch_bounds__(256) void k_init(int* __restrict__ bhist,
                                              int* __restrict__ bcursor,
                                              float* __restrict__ g,
                                              int* __restrict__ gcnt,
                                              const float* __restrict__ W1,
                                              const float* __restrict__ W2,
                                              _Float16* __restrict__ Wt1,
                                              _Float16* __restrict__ Wt2) {
    int tid = threadIdx.x;
    if (blockIdx.x == 0) {
        bhist[tid] = 0; bcursor[tid] = 0;
        for (int i = tid; i < NG * 64; i += 256) g[i] = 0.f;
        if (tid < NG) gcnt[tid] = 0;
    }
    int idx = blockIdx.x * 256 + tid;
    if (idx < 128 * 128) {
        int n = idx % 128, k = idx / 128;
        Wt1[n * K128 + k] = (_Float16)W1[k * 128 + n];
    } else if (idx < 128 * 128 + 64 * 128) {
        int i = idx - 128 * 128;
        int n = i % 64, k = i / 64;
        Wt2[n * K128 + k] = (_Float16)W2[k * 64 + n];
    }
}

// ================================================================ CSR build
__global__ __launch_bounds__(256) void k_bhist(const int* __restrict__ col,
                                               int* __restrict__ bhist, int E, int nbk) {
    __shared__ int h[BKB];
    int tid = threadIdx.x;
    for (int i = tid; i < nbk; i += 256) h[i] = 0;
    __syncthreads();
    int base = blockIdx.x * 1024 + tid * 4;
#pragma unroll
    for (int q = 0; q < 4; q++) {
        int e = base + q;
        if (e < E) atomicAdd(&h[col[e] >> 8], 1);
    }
    __syncthreads();
    for (int i = tid; i < nbk; i += 256) if (h[i]) atomicAdd(&bhist[i], h[i]);
}

__global__ __launch_bounds__(256) void k_bucket(const int* __restrict__ row,
                                                const int* __restrict__ col,
                                                const float* __restrict__ ew,
                                                const int* __restrict__ bhist,
                                                int* __restrict__ bcursor,
                                                uint2* __restrict__ bk, int E, int nbk) {
    __shared__ int part[256];
    __shared__ int h[BKB];
    __shared__ int cur[BKB];
    int tid = threadIdx.x;
    int gh = (tid < nbk) ? bhist[tid] : 0;
    part[tid] = gh;
    h[tid] = 0;
    __syncthreads();
    for (int off = 1; off < 256; off <<= 1) {
        int t = (tid >= off) ? part[tid - off] : 0;
        __syncthreads();
        part[tid] += t;
        __syncthreads();
    }
    int ex = part[tid] - gh;
    int base = blockIdx.x * 1024 + tid * 4;
    int c[4];
#pragma unroll
    for (int q = 0; q < 4; q++) {
        int e = base + q;
        c[q] = (e < E) ? col[e] : -1;
        if (c[q] >= 0) atomicAdd(&h[c[q] >> 8], 1);
    }
    __syncthreads();
    if (tid < nbk) cur[tid] = h[tid] ? ex + atomicAdd(&bcursor[tid], h[tid]) : 0;
    __syncthreads();
#pragma unroll
    for (int q = 0; q < 4; q++) {
        int e = base + q;
        if (c[q] >= 0) {
            int slot = atomicAdd(&cur[c[q] >> 8], 1);
            bk[slot] = make_uint2(((unsigned)c[q] << 16) | (unsigned)row[e],
                                  __float_as_uint(ew[e]));
        }
    }
}

__global__ __launch_bounds__(256) void k_colsedata(const uint2* __restrict__ bk,
                                                   const int* __restrict__ bhist,
                                                   float* __restrict__ dis,
                                                   int* __restrict__ rs,
                                                   unsigned* __restrict__ edata,
                                                   int N, int E, int nbk) {
    __shared__ int part[256];
    __shared__ float sdeg[BKB];
    __shared__ int scnt[BKB];
    __shared__ int cur[BKB];
    __shared__ float sdis[BKB];
    __shared__ int sse[2];
    int b = blockIdx.x, tid = threadIdx.x;
    int gh = (tid < nbk) ? bhist[tid] : 0;
    part[tid] = gh;
    sdeg[tid] = 0.f; scnt[tid] = 0;
    __syncthreads();
    for (int off = 1; off < 256; off <<= 1) {
        int t = (tid >= off) ? part[tid - off] : 0;
        __syncthreads();
        part[tid] += t;
        __syncthreads();
    }
    if (tid == b) { sse[0] = part[tid] - gh; sse[1] = part[tid]; }
    __syncthreads();
    int s = sse[0], e = sse[1];
    for (int i = s + tid; i < e; i += 256) {
        uint2 q = bk[i];
        int c8 = (q.x >> 16) & 255;
        atomicAdd(&sdeg[c8], __uint_as_float(q.y));
        atomicAdd(&scnt[c8], 1);
    }
    __syncthreads();
    int cnt = scnt[tid];
    part[tid] = cnt;
    __syncthreads();
    for (int off = 1; off < 256; off <<= 1) {
        int t = (tid >= off) ? part[tid - off] : 0;
        __syncthreads();
        part[tid] += t;
        __syncthreads();
    }
    float d  = rsqrtf(sdeg[tid] + 1.0f);
    int   r0 = s + part[tid] - cnt;
    int gcol = b * BKB + tid;
    if (gcol < N) { dis[gcol] = d; rs[gcol] = r0; }
    if (b == 0 && tid == 0) rs[N] = E;
    cur[tid] = r0; sdis[tid] = d;
    __syncthreads();
    for (int i = s + tid; i < e; i += 256) {
        uint2 q = bk[i];
        int c8 = (q.x >> 16) & 255;
        unsigned r = q.x & 0xFFFFu;
        _Float16 wh = (_Float16)(__uint_as_float(q.y) * sdis[c8]);
        int pos = atomicAdd(&cur[c8], 1);
        edata[pos] = (r << 16) | (unsigned)__builtin_bit_cast(unsigned short, wh);
    }
}

// ------------------------------------------------- MFMA fp16 GEMM (layer1), dis epilogue
__global__ __launch_bounds__(256) void k_gemm1(const float* __restrict__ A,
                                               const _Float16* __restrict__ Wt,
                                               const float* __restrict__ dis,
                                               _Float16* __restrict__ out, int M) {
    constexpr int NCOL = 128, AS = 136;
    __shared__ _Float16 Ah[64 * AS];
    __shared__ _Float16 Wh[NCOL * AS];

    int tid  = threadIdx.x;
    int row0 = blockIdx.x * 64;
#pragma unroll
    for (int q = 0; q < 8; q++) {
        int idx = tid + 256 * q;
        int r = idx >> 5, c4 = (idx & 31) * 4;
        float4 v = ld4(A + (size_t)(row0 + r) * K128 + c4);
        sth4(&Ah[r * AS + c4], v);
    }
#pragma unroll
    for (int q = 0; q < NCOL / 16; q++) {
        int idx = tid + 256 * q;
        int n = idx >> 4, c8 = (idx & 15) * 8;
        *(half8*)&Wh[n * AS + c8] = *(const half8*)(Wt + n * K128 + c8);
    }
    __syncthreads();

    int lane = tid & 63, wv = tid >> 6, m = lane & 15, quad = lane >> 4;
    f32x4 acc[NCOL / 16];
#pragma unroll
    for (int ct = 0; ct < NCOL / 16; ct++) acc[ct] = (f32x4){0.f, 0.f, 0.f, 0.f};
#pragma unroll
    for (int kt = 0; kt < 4; kt++) {
        half8 af = *(const half8*)&Ah[(wv * 16 + m) * AS + kt * 32 + quad * 8];
#pragma unroll
        for (int ct = 0; ct < NCOL / 16; ct++) {
            half8 bf = *(const half8*)&Wh[(ct * 16 + m) * AS + kt * 32 + quad * 8];
            acc[ct] = __builtin_amdgcn_mfma_f32_16x16x32_f16(af, bf, acc[ct], 0, 0, 0);
        }
    }
    float d[4];
#pragma unroll
    for (int r = 0; r < 4; r++) d[r] = dis[row0 + wv * 16 + quad * 4 + r];
#pragma unroll
    for (int ct = 0; ct < NCOL / 16; ct++)
#pragma unroll
        for (int r = 0; r < 4; r++) {
            int grow = row0 + wv * 16 + quad * 4 + r;
            out[(size_t)grow * NCOL + ct * 16 + m] = (_Float16)(acc[ct][r] * d[r]);
        }
}

// ------------------------------------------------- fused agg(F=128) + gemm2 (MFMA)
// Phase 1 gather now 8-way ILP (8 loads in flight; was 4 — R9 pattern).
__global__ __launch_bounds__(256) void k_agg_gemm(const _Float16* __restrict__ xw,
                                                  const float* __restrict__ dis,
                                                  const unsigned* __restrict__ edata,
                                                  const int* __restrict__ rs,
                                                  const float* __restrict__ bias,
                                                  const _Float16* __restrict__ Wt2,
                                                  _Float16* __restrict__ xw2, int N) {
    constexpr int F = 128, AS = 136;
    __shared__ _Float16 Hs[16 * AS];
    __shared__ _Float16 Ws[64 * AS];

    int tid   = threadIdx.x;
    int node0 = blockIdx.x * 16;
    int nl    = tid >> 4;
    int node  = node0 + nl;
    int j8    = (tid & 15) * 8;

#pragma unroll
    for (int q = 0; q < 4; q++) {
        int idx = tid + 256 * q;
        int n = idx >> 4, c8 = (idx & 15) * 8;
        *(half8*)&Ws[n * AS + c8] = *(const half8*)(Wt2 + n * K128 + c8);
    }

    float a0[8], a1[8], a2[8], a3[8], a4[8], a5[8], a6[8], a7[8];
    {
        float dv = dis[node];
        half8 sv = *(const half8*)(xw + (size_t)node * F + j8);
        float4 bA = ld4(bias + j8), bB = ld4(bias + j8 + 4);
#pragma unroll
        for (int t = 0; t < 4; t++) { a0[t] = (float)sv[t] * dv + (&bA.x)[t];
                                      a0[t + 4] = (float)sv[t + 4] * dv + (&bB.x)[t]; }
#pragma unroll
        for (int t = 0; t < 8; t++) { a1[t] = 0.f; a2[t] = 0.f; a3[t] = 0.f;
                                      a4[t] = 0.f; a5[t] = 0.f; a6[t] = 0.f; a7[t] = 0.f; }
    }
    int s = rs[node], e = rs[node + 1];
    int j = s;
    for (; j + 8 <= e; j += 8) {
        unsigned q0 = edata[j + 0], q1 = edata[j + 1], q2 = edata[j + 2], q3 = edata[j + 3];
        unsigned q4 = edata[j + 4], q5 = edata[j + 5], q6 = edata[j + 6], q7 = edata[j + 7];
        half8 v0 = *(const half8*)(xw + (size_t)(q0 >> 16) * F + j8);
        half8 v1 = *(const half8*)(xw + (size_t)(q1 >> 16) * F + j8);
        half8 v2 = *(const half8*)(xw + (size_t)(q2 >> 16) * F + j8);
        half8 v3 = *(const half8*)(xw + (size_t)(q3 >> 16) * F + j8);
        half8 v4 = *(const half8*)(xw + (size_t)(q4 >> 16) * F + j8);
        half8 v5 = *(const half8*)(xw + (size_t)(q5 >> 16) * F + j8);
        half8 v6 = *(const half8*)(xw + (size_t)(q6 >> 16) * F + j8);
        half8 v7 = *(const half8*)(xw + (size_t)(q7 >> 16) * F + j8);
        float n0 = unpack_w(q0), n1 = unpack_w(q1), n2 = unpack_w(q2), n3 = unpack_w(q3);
        float n4 = unpack_w(q4), n5 = unpack_w(q5), n6 = unpack_w(q6), n7 = unpack_w(q7);
#pragma unroll
        for (int t = 0; t < 8; t++) {
            a0[t] += n0 * (float)v0[t];
            a1[t] += n1 * (float)v1[t];
            a2[t] += n2 * (float)v2[t];
            a3[t] += n3 * (float)v3[t];
            a4[t] += n4 * (float)v4[t];
            a5[t] += n5 * (float)v5[t];
            a6[t] += n6 * (float)v6[t];
            a7[t] += n7 * (float)v7[t];
        }
    }
    for (; j + 4 <= e; j += 4) {
        unsigned q0 = edata[j + 0], q1 = edata[j + 1], q2 = edata[j + 2], q3 = edata[j + 3];
        half8 v0 = *(const half8*)(xw + (size_t)(q0 >> 16) * F + j8);
        half8 v1 = *(const half8*)(xw + (size_t)(q1 >> 16) * F + j8);
        half8 v2 = *(const half8*)(xw + (size_t)(q2 >> 16) * F + j8);
        half8 v3 = *(const half8*)(xw + (size_t)(q3 >> 16) * F + j8);
        float n0 = unpack_w(q0), n1 = unpack_w(q1), n2 = unpack_w(q2), n3 = unpack_w(q3);
#pragma unroll
        for (int t = 0; t < 8; t++) {
            a0[t] += n0 * (float)v0[t];
            a1[t] += n1 * (float)v1[t];
            a2[t] += n2 * (float)v2[t];
            a3[t] += n3 * (float)v3[t];
        }
    }
    for (; j < e; j++) {
        unsigned q = edata[j];
        half8 v = *(const half8*)(xw + (size_t)(q >> 16) * F + j8);
        float nm = unpack_w(q);
#pragma unroll
        for (int t = 0; t < 8; t++) a0[t] += nm * (float)v[t];
    }
    half8 hv;
#pragma unroll
    for (int t = 0; t < 8; t++)
        hv[t] = (_Float16)fmaxf(((a0[t] + a1[t]) + (a2[t] + a3[t])) +
                                ((a4[t] + a5[t]) + (a6[t] + a7[t])), 0.f);
    *(half8*)&Hs[nl * AS + j8] = hv;
    __syncthreads();

    int lane = tid & 63, wv = tid >> 6, m = lane & 15, quad = lane >> 4;
    f32x4 acc = (f32x4){0.f, 0.f, 0.f, 0.f};
#pragma unroll
    for (int kt = 0; kt < 4; kt++) {
        half8 af = *(const half8*)&Hs[m * AS + kt * 32 + quad * 8];
        half8 bf = *(const half8*)&Ws[(wv * 16 + m) * AS + kt * 32 + quad * 8];
        acc = __builtin_amdgcn_mfma_f32_16x16x32_f16(af, bf, acc, 0, 0, 0);
    }
#pragma unroll
    for (int r = 0; r < 4; r++) {
        int gn = node0 + quad * 4 + r;
        xw2[(size_t)gn * 64 + wv * 16 + m] = (_Float16)(acc[r] * dis[gn]);
    }
}

// ------------------------------------------------- agg F=64 + mean-pool, 8-way ILP
__global__ __launch_bounds__(256) void k_agg_pool(const _Float16* __restrict__ xw,
                                                  const float* __restrict__ dis,
                                                  const unsigned* __restrict__ edata,
                                                  const int* __restrict__ rs,
                                                  const float* __restrict__ bias,
                                                  const int* __restrict__ batch,
                                                  float* __restrict__ g,
                                                  int* __restrict__ gcnt, int N) {
    constexpr int F = 64;
    __shared__ float T[16][F + 4];
    __shared__ int sb[16];
    int tid  = threadIdx.x;
    int base = blockIdx.x * 16;
    int nl   = tid >> 4;
    int node = base + nl;
    int j4   = (tid & 15) * 4;
    if (tid < 16) sb[tid] = batch[base + tid];

    float dv = dis[node];
    float4 self = ldh4(xw + (size_t)node * F + j4);
    float4 bv   = ld4(bias + j4);
    float4 a0 = make_float4(self.x * dv + bv.x, self.y * dv + bv.y,
                            self.z * dv + bv.z, self.w * dv + bv.w);
    float4 a1 = make_float4(0.f, 0.f, 0.f, 0.f);
    float4 a2 = a1, a3 = a1, a4 = a1, a5 = a1, a6 = a1, a7 = a1;
    int s = rs[node], e = rs[node + 1];
    int j = s;
    for (; j + 8 <= e; j += 8) {
        unsigned q0 = edata[j + 0], q1 = edata[j + 1], q2 = edata[j + 2], q3 = edata[j + 3];
        unsigned q4 = edata[j + 4], q5 = edata[j + 5], q6 = edata[j + 6], q7 = edata[j + 7];
        float4 v0 = ldh4(xw + (size_t)(q0 >> 16) * F + j4);
        float4 v1 = ldh4(xw + (size_t)(q1 >> 16) * F + j4);
        float4 v2 = ldh4(xw + (size_t)(q2 >> 16) * F + j4);
        float4 v3 = ldh4(xw + (size_t)(q3 >> 16) * F + j4);
        float4 v4 = ldh4(xw + (size_t)(q4 >> 16) * F + j4);
        float4 v5 = ldh4(xw + (size_t)(q5 >> 16) * F + j4);
        float4 v6 = ldh4(xw + (size_t)(q6 >> 16) * F + j4);
        float4 v7 = ldh4(xw + (size_t)(q7 >> 16) * F + j4);
        float n0 = unpack_w(q0), n1 = unpack_w(q1), n2 = unpack_w(q2), n3 = unpack_w(q3);
        float n4 = unpack_w(q4), n5 = unpack_w(q5), n6 = unpack_w(q6), n7 = unpack_w(q7);
        a0.x += n0 * v0.x; a0.y += n0 * v0.y; a0.z += n0 * v0.z; a0.w += n0 * v0.w;
        a1.x += n1 * v1.x; a1.y += n1 * v1.y; a1.z += n1 * v1.z; a1.w += n1 * v1.w;
        a2.x += n2 * v2.x; a2.y += n2 * v2.y; a2.z += n2 * v2.z; a2.w += n2 * v2.w;
        a3.x += n3 * v3.x; a3.y += n3 * v3.y; a3.z += n3 * v3.z; a3.w += n3 * v3.w;
        a4.x += n4 * v4.x; a4.y += n4 * v4.y; a4.z += n4 * v4.z; a4.w += n4 * v4.w;
        a5.x += n5 * v5.x; a5.y += n5 * v5.y; a5.z += n5 * v5.z; a5.w += n5 * v5.w;
        a6.x += n6 * v6.x; a6.y += n6 * v6.y; a6.z += n6 * v6.z; a6.w += n6 * v6.w;
        a7.x += n7 * v7.x; a7.y += n7 * v7.y; a7.z += n7 * v7.z; a7.w += n7 * v7.w;
    }
    for (; j + 4 <= e; j += 4) {
        unsigned q0 = edata[j + 0], q1 = edata[j + 1], q2 = edata[j + 2], q3 = edata[j + 3];
        float4 v0 = ldh4(xw + (size_t)(q0 >> 16) * F + j4);
        float4 v1 = ldh4(xw + (size_t)(q1 >> 16) * F + j4);
        float4 v2 = ldh4(xw + (size_t)(q2 >> 16) * F + j4);
        float4 v3 = ldh4(xw + (size_t)(q3 >> 16) * F + j4);
        float n0 = unpack_w(q0), n1 = unpack_w(q1), n2 = unpack_w(q2), n3 = unpack_w(q3);
        a0.x += n0 * v0.x; a0.y += n0 * v0.y; a0.z += n0 * v0.z; a0.w += n0 * v0.w;
        a1.x += n1 * v1.x; a1.y += n1 * v1.y; a1.z += n1 * v1.z; a1.w += n1 * v1.w;
        a2.x += n2 * v2.x; a2.y += n2 * v2.y; a2.z += n2 * v2.z; a2.w += n2 * v2.w;
        a3.x += n3 * v3.x; a3.y += n3 * v3.y; a3.z += n3 * v3.z; a3.w += n3 * v3.w;
    }
    for (; j < e; j++) {
        unsigned q = edata[j];
        float nm = unpack_w(q);
        float4 v = ldh4(xw + (size_t)(q >> 16) * F + j4);
        a0.x += nm * v.x; a0.y += nm * v.y; a0.z += nm * v.z; a0.w += nm * v.w;
    }
    T[nl][j4 + 0] = fmaxf(((a0.x + a1.x) + (a2.x + a3.x)) + ((a4.x + a5.x) + (a6.x + a7.x)), 0.f);
    T[nl][j4 + 1] = fmaxf(((a0.y + a1.y) + (a2.y + a3.y)) + ((a4.y + a5.y) + (a6.y + a7.y)), 0.f);
    T[nl][j4 + 2] = fmaxf(((a0.z + a1.z) + (a2.z + a3.z)) + ((a4.z + a5.z) + (a6.z + a7.z)), 0.f);
    T[nl][j4 + 3] = fmaxf(((a0.w + a1.w) + (a2.w + a3.w)) + ((a4.w + a5.w) + (a6.w + a7.w)), 0.f);
    __syncthreads();
    if (tid < 64) {
        int f = tid;
        float run = 0.f;
        int cur = -1, cnt = 0;
        for (int k = 0; k < 16; k++) {
            int b = sb[k];
            if (b != cur) {
                if (cur >= 0) {
                    atomicAdd(&g[cur * 64 + f], run);
                    if (f == 0) atomicAdd(&gcnt[cur], cnt);
                }
                cur = b; run = 0.f; cnt = 0;
            }
            run += T[k][f];
            cnt++;
        }
        atomicAdd(&g[cur * 64 + f], run);
        if (f == 0) atomicAdd(&gcnt[cur], cnt);
    }
}

// ------------------------------------------------- FC: out[NG,FLAT] = (g/cnt) @ Wfc + bfc
__global__ __launch_bounds__(256) void k_fc(const float* __restrict__ g,
                                            const int* __restrict__ gcnt,
                                            const float* __restrict__ Wfc,
                                            const float* __restrict__ bfc,
                                            float* __restrict__ out) {
    __shared__ float gs[64];
    int i = blockIdx.y;
    int j = blockIdx.x * blockDim.x + threadIdx.x;
    if (threadIdx.x < 64) {
        float c = (float)gcnt[i];
        gs[threadIdx.x] = g[i * 64 + threadIdx.x] / fmaxf(c, 1.0f);
    }
    __syncthreads();
    if (j >= FLAT) return;
    float acc = bfc[j];
#pragma unroll 8
    for (int k = 0; k < 64; k++) acc += gs[k] * Wfc[k * FLAT + j];
    out[(size_t)i * FLAT + j] = acc;
}

// ================================================================ launcher
extern "C" void kernel_launch(void* const* d_in, const int* in_sizes, int n_in,
                              void* d_out, int out_size, void* d_ws, size_t ws_size,
                              hipStream_t stream) {
    const float* x    = (const float*)d_in[0];
    const int*   ei   = (const int*)d_in[1];
    const float* ew   = (const float*)d_in[2];
    const int*   batch= (const int*)d_in[3];
    const float* W1   = (const float*)d_in[4];
    const float* b1   = (const float*)d_in[5];
    const float* W2   = (const float*)d_in[6];
    const float* b2   = (const float*)d_in[7];
    const float* Wfc  = (const float*)d_in[8];
    const float* bfc  = (const float*)d_in[9];
    float* out = (float*)d_out;

    const int N = in_sizes[0] / K128;   // 40000
    const int E = in_sizes[2];          // 640000
    const int* row = ei;
    const int* col = ei + E;
    const int nbk = (N + BKB - 1) / BKB;   // 157 buckets
    const int neb = (E + 1023) / 1024;     // edge-chunk blocks

    // ---- workspace carve (256B aligned)
    char* p = (char*)d_ws;
    auto alloc = [&](size_t bytes) -> void* {
        void* r = (void*)p;
        p += (bytes + 255) & ~(size_t)255;
        return r;
    };
    float*     dis   = (float*)    alloc((size_t)N * 4);
    int*       rs    = (int*)      alloc((size_t)(N + 1) * 4);
    uint2*     bk    = (uint2*)    alloc((size_t)E * 8);
    unsigned*  edata = (unsigned*) alloc((size_t)E * 4);
    _Float16*  xw1   = (_Float16*) alloc((size_t)N * 128 * 2);
    _Float16*  xw2   = (_Float16*) alloc((size_t)N * 64 * 2);
    _Float16*  Wt1   = (_Float16*) alloc((size_t)128 * 128 * 2);
    _Float16*  Wt2   = (_Float16*) alloc((size_t)64 * 128 * 2);
    float*     g     = (float*)    alloc(64 * 64 * 4);
    int*       gcnt  = (int*)      alloc(64 * 4);
    int*       bhist = (int*)      alloc(BKB * 4);
    int*       bcur  = (int*)      alloc(BKB * 4);

    // ---- 8 dispatches total
    k_init     <<<96,  256, 0, stream>>>(bhist, bcur, g, gcnt, W1, W2, Wt1, Wt2);
    k_bhist    <<<neb, 256, 0, stream>>>(col, bhist, E, nbk);
    k_bucket   <<<neb, 256, 0, stream>>>(row, col, ew, bhist, bcur, bk, E, nbk);
    k_colsedata<<<nbk, 256, 0, stream>>>(bk, bhist, dis, rs, edata, N, E, nbk);

    k_gemm1    <<<N / 64, 256, 0, stream>>>(x, Wt1, dis, xw1, N);
    k_agg_gemm <<<N / 16, 256, 0, stream>>>(xw1, dis, edata, rs, b1, Wt2, xw2, N);
    k_agg_pool <<<N / 16, 256, 0, stream>>>(xw2, dis, edata, rs, b2, batch, g, gcnt, N);

    dim3 fcg((FLAT + 255) / 256, NG);
    k_fc<<<fcg, 256, 0, stream>>>(g, gcnt, Wfc, bfc, out);
}

// Round 13
// 196.208 us; speedup vs baseline: 1.0417x; 1.0417x over previous
//
#include <hip/hip_runtime.h>
#include <hip/hip_bf16.h>
#include <hip/hip_fp16.h>
#include <type_traits>

#define NG 64          // number of graphs
#define FLAT 2904      // FC output width
#define K128 128       // inner dim for both GEMMs
#define BKB 256        // cols per bucket (col >> 8)

typedef _Float16 h4 __attribute__((ext_vector_type(4)));     // 8B
typedef _Float16 half8 __attribute__((ext_vector_type(8)));  // 16B MFMA frag
typedef float f32x4 __attribute__((ext_vector_type(4)));

// ---------------------------------------------------------------- utilities
__device__ __forceinline__ float4 ld4(const float* p) { return *(const float4*)p; }
__device__ __forceinline__ float4 ldh4(const _Float16* p) {
    h4 h = *(const h4*)p;
    return make_float4((float)h.x, (float)h.y, (float)h.z, (float)h.w);
}
__device__ __forceinline__ void sth4(_Float16* p, float4 v) {
    h4 h; h.x = (_Float16)v.x; h.y = (_Float16)v.y; h.z = (_Float16)v.z; h.w = (_Float16)v.w;
    *(h4*)p = h;
}
__device__ __forceinline__ float unpack_w(unsigned q) {
    return (float)__builtin_bit_cast(_Float16, (unsigned short)(q & 0xFFFFu));
}

// ------------------------------------------------- init: zero accum + both W converts
// block 0 zeroes bhist/bcursor/g/gcnt; all 96 blocks share the wconv work.
__global__ __launch_bounds__(256) void k_init(int* __restrict__ bhist,
                                              int* __restrict__ bcursor,
                                              float* __restrict__ g,
                                              int* __restrict__ gcnt,
                                              const float* __restrict__ W1,
                                              const float* __restrict__ W2,
                                              _Float16* __restrict__ Wt1,
                                              _Float16* __restrict__ Wt2) {
    int tid = threadIdx.x;
    if (blockIdx.x == 0) {
        bhist[tid] = 0; bcursor[tid] = 0;
        for (int i = tid; i < NG * 64; i += 256) g[i] = 0.f;
        if (tid < NG) gcnt[tid] = 0;
    }
    int idx = blockIdx.x * 256 + tid;
    if (idx < 128 * 128) {
        int n = idx % 128, k = idx / 128;
        Wt1[n * K128 + k] = (_Float16)W1[k * 128 + n];
    } else if (idx < 128 * 128 + 64 * 128) {
        int i = idx - 128 * 128;
        int n = i % 64, k = i / 64;
        Wt2[n * K128 + k] = (_Float16)W2[k * 64 + n];
    }
}

// ================================================================ CSR build
// bucket counting sort; per-block redundant 157-entry scan of bhist replaces
// the k_bscan dispatch. edata = (row<<16)|fp16(w'), w' = ew*dis[col].

__global__ __launch_bounds__(256) void k_bhist(const int* __restrict__ col,
                                               int* __restrict__ bhist, int E, int nbk) {
    __shared__ int h[BKB];
    int tid = threadIdx.x;
    for (int i = tid; i < nbk; i += 256) h[i] = 0;
    __syncthreads();
    int base = blockIdx.x * 1024 + tid * 4;
#pragma unroll
    for (int q = 0; q < 4; q++) {
        int e = base + q;
        if (e < E) atomicAdd(&h[col[e] >> 8], 1);
    }
    __syncthreads();
    for (int i = tid; i < nbk; i += 256) if (h[i]) atomicAdd(&bhist[i], h[i]);
}

__global__ __launch_bounds__(256) void k_bucket(const int* __restrict__ row,
                                                const int* __restrict__ col,
                                                const float* __restrict__ ew,
                                                const int* __restrict__ bhist,
                                                int* __restrict__ bcursor,
                                                uint2* __restrict__ bk, int E, int nbk) {
    __shared__ int part[256];
    __shared__ int h[BKB];
    __shared__ int cur[BKB];
    int tid = threadIdx.x;
    int gh = (tid < nbk) ? bhist[tid] : 0;
    part[tid] = gh;
    h[tid] = 0;
    __syncthreads();
    for (int off = 1; off < 256; off <<= 1) {
        int t = (tid >= off) ? part[tid - off] : 0;
        __syncthreads();
        part[tid] += t;
        __syncthreads();
    }
    int ex = part[tid] - gh;                  // exclusive global bucket base
    int base = blockIdx.x * 1024 + tid * 4;
    int c[4];
#pragma unroll
    for (int q = 0; q < 4; q++) {
        int e = base + q;
        c[q] = (e < E) ? col[e] : -1;
        if (c[q] >= 0) atomicAdd(&h[c[q] >> 8], 1);
    }
    __syncthreads();
    if (tid < nbk) cur[tid] = h[tid] ? ex + atomicAdd(&bcursor[tid], h[tid]) : 0;
    __syncthreads();
#pragma unroll
    for (int q = 0; q < 4; q++) {
        int e = base + q;
        if (c[q] >= 0) {
            int slot = atomicAdd(&cur[c[q] >> 8], 1);
            bk[slot] = make_uint2(((unsigned)c[q] << 16) | (unsigned)row[e],
                                  __float_as_uint(ew[e]));
        }
    }
}

// ---- fused: bucket base (local scan) -> degree/count -> dis/rs -> edata
__global__ __launch_bounds__(256) void k_colsedata(const uint2* __restrict__ bk,
                                                   const int* __restrict__ bhist,
                                                   float* __restrict__ dis,
                                                   int* __restrict__ rs,
                                                   unsigned* __restrict__ edata,
                                                   int N, int E, int nbk) {
    __shared__ int part[256];
    __shared__ float sdeg[BKB];
    __shared__ int scnt[BKB];
    __shared__ int cur[BKB];
    __shared__ float sdis[BKB];
    __shared__ int sse[2];
    int b = blockIdx.x, tid = threadIdx.x;
    int gh = (tid < nbk) ? bhist[tid] : 0;
    part[tid] = gh;
    sdeg[tid] = 0.f; scnt[tid] = 0;
    __syncthreads();
    for (int off = 1; off < 256; off <<= 1) {
        int t = (tid >= off) ? part[tid - off] : 0;
        __syncthreads();
        part[tid] += t;
        __syncthreads();
    }
    if (tid == b) { sse[0] = part[tid] - gh; sse[1] = part[tid]; }
    __syncthreads();
    int s = sse[0], e = sse[1];
    for (int i = s + tid; i < e; i += 256) {
        uint2 q = bk[i];
        int c8 = (q.x >> 16) & 255;
        atomicAdd(&sdeg[c8], __uint_as_float(q.y));
        atomicAdd(&scnt[c8], 1);
    }
    __syncthreads();
    int cnt = scnt[tid];
    part[tid] = cnt;
    __syncthreads();
    for (int off = 1; off < 256; off <<= 1) {
        int t = (tid >= off) ? part[tid - off] : 0;
        __syncthreads();
        part[tid] += t;
        __syncthreads();
    }
    float d  = rsqrtf(sdeg[tid] + 1.0f);
    int   r0 = s + part[tid] - cnt;
    int gcol = b * BKB + tid;
    if (gcol < N) { dis[gcol] = d; rs[gcol] = r0; }
    if (b == 0 && tid == 0) rs[N] = E;
    cur[tid] = r0; sdis[tid] = d;
    __syncthreads();
    for (int i = s + tid; i < e; i += 256) {
        uint2 q = bk[i];
        int c8 = (q.x >> 16) & 255;
        unsigned r = q.x & 0xFFFFu;
        _Float16 wh = (_Float16)(__uint_as_float(q.y) * sdis[c8]);  // ew*dis[col]
        int pos = atomicAdd(&cur[c8], 1);
        edata[pos] = (r << 16) | (unsigned)__builtin_bit_cast(unsigned short, wh);
    }
}

// ------------------------------------------------- MFMA fp16 GEMM (layer1), dis epilogue
// out[r] = dis[r] * (A[r] @ W)  stored fp16.
__global__ __launch_bounds__(256) void k_gemm1(const float* __restrict__ A,
                                               const _Float16* __restrict__ Wt,
                                               const float* __restrict__ dis,
                                               _Float16* __restrict__ out, int M) {
    constexpr int NCOL = 128, AS = 136;
    __shared__ _Float16 Ah[64 * AS];
    __shared__ _Float16 Wh[NCOL * AS];

    int tid  = threadIdx.x;
    int row0 = blockIdx.x * 64;
#pragma unroll
    for (int q = 0; q < 8; q++) {
        int idx = tid + 256 * q;
        int r = idx >> 5, c4 = (idx & 31) * 4;
        float4 v = ld4(A + (size_t)(row0 + r) * K128 + c4);
        sth4(&Ah[r * AS + c4], v);
    }
#pragma unroll
    for (int q = 0; q < NCOL / 16; q++) {
        int idx = tid + 256 * q;
        int n = idx >> 4, c8 = (idx & 15) * 8;
        *(half8*)&Wh[n * AS + c8] = *(const half8*)(Wt + n * K128 + c8);
    }
    __syncthreads();

    int lane = tid & 63, wv = tid >> 6, m = lane & 15, quad = lane >> 4;
    f32x4 acc[NCOL / 16];
#pragma unroll
    for (int ct = 0; ct < NCOL / 16; ct++) acc[ct] = (f32x4){0.f, 0.f, 0.f, 0.f};
#pragma unroll
    for (int kt = 0; kt < 4; kt++) {
        half8 af = *(const half8*)&Ah[(wv * 16 + m) * AS + kt * 32 + quad * 8];
#pragma unroll
        for (int ct = 0; ct < NCOL / 16; ct++) {
            half8 bf = *(const half8*)&Wh[(ct * 16 + m) * AS + kt * 32 + quad * 8];
            acc[ct] = __builtin_amdgcn_mfma_f32_16x16x32_f16(af, bf, acc[ct], 0, 0, 0);
        }
    }
    float d[4];
#pragma unroll
    for (int r = 0; r < 4; r++) d[r] = dis[row0 + wv * 16 + quad * 4 + r];
#pragma unroll
    for (int ct = 0; ct < NCOL / 16; ct++)
#pragma unroll
        for (int r = 0; r < 4; r++) {
            int grow = row0 + wv * 16 + quad * 4 + r;
            out[(size_t)grow * NCOL + ct * 16 + m] = (_Float16)(acc[ct][r] * d[r]);
        }
}

// ------------------------------------------------- fused agg(F=128) + gemm2 (MFMA)
// 16 nodes/block. Phase 1: gather h1 rows (relu) into LDS tile (h1 never hits
// memory), 4-way ILP (8-way regressed: VGPR pressure past 128 halves
// occupancy — R12). Phase 2: xw2[16x64] = dis * (h1_tile @ W2) via MFMA.
__global__ __launch_bounds__(256) void k_agg_gemm(const _Float16* __restrict__ xw,
                                                  const float* __restrict__ dis,
                                                  const unsigned* __restrict__ edata,
                                                  const int* __restrict__ rs,
                                                  const float* __restrict__ bias,
                                                  const _Float16* __restrict__ Wt2,
                                                  _Float16* __restrict__ xw2, int N) {
    constexpr int F = 128, AS = 136;
    __shared__ _Float16 Hs[16 * AS];
    __shared__ _Float16 Ws[64 * AS];

    int tid   = threadIdx.x;
    int node0 = blockIdx.x * 16;
    int nl    = tid >> 4;            // 0..15
    int node  = node0 + nl;
    int j8    = (tid & 15) * 8;

    // stage Wt2 (64 x 128 fp16)
#pragma unroll
    for (int q = 0; q < 4; q++) {
        int idx = tid + 256 * q;
        int n = idx >> 4, c8 = (idx & 15) * 8;
        *(half8*)&Ws[n * AS + c8] = *(const half8*)(Wt2 + n * K128 + c8);
    }

    // ---- phase 1: gather. 4 independent accumulators x 8 features.
    float a0[8], a1[8], a2[8], a3[8];
    {
        float dv = dis[node];
        half8 sv = *(const half8*)(xw + (size_t)node * F + j8);
        float4 bA = ld4(bias + j8), bB = ld4(bias + j8 + 4);
#pragma unroll
        for (int t = 0; t < 4; t++) { a0[t] = (float)sv[t] * dv + (&bA.x)[t];
                                      a0[t + 4] = (float)sv[t + 4] * dv + (&bB.x)[t]; }
#pragma unroll
        for (int t = 0; t < 8; t++) { a1[t] = 0.f; a2[t] = 0.f; a3[t] = 0.f; }
    }
    int s = rs[node], e = rs[node + 1];
    int j = s;
    for (; j + 4 <= e; j += 4) {
        unsigned q0 = edata[j + 0], q1 = edata[j + 1], q2 = edata[j + 2], q3 = edata[j + 3];
        half8 v0 = *(const half8*)(xw + (size_t)(q0 >> 16) * F + j8);
        half8 v1 = *(const half8*)(xw + (size_t)(q1 >> 16) * F + j8);
        half8 v2 = *(const half8*)(xw + (size_t)(q2 >> 16) * F + j8);
        half8 v3 = *(const half8*)(xw + (size_t)(q3 >> 16) * F + j8);
        float n0 = unpack_w(q0), n1 = unpack_w(q1), n2 = unpack_w(q2), n3 = unpack_w(q3);
#pragma unroll
        for (int t = 0; t < 8; t++) {
            a0[t] += n0 * (float)v0[t];
            a1[t] += n1 * (float)v1[t];
            a2[t] += n2 * (float)v2[t];
            a3[t] += n3 * (float)v3[t];
        }
    }
    for (; j < e; j++) {
        unsigned q = edata[j];
        half8 v = *(const half8*)(xw + (size_t)(q >> 16) * F + j8);
        float nm = unpack_w(q);
#pragma unroll
        for (int t = 0; t < 8; t++) a0[t] += nm * (float)v[t];
    }
    half8 hv;
#pragma unroll
    for (int t = 0; t < 8; t++)
        hv[t] = (_Float16)fmaxf((a0[t] + a1[t]) + (a2[t] + a3[t]), 0.f);
    *(half8*)&Hs[nl * AS + j8] = hv;
    __syncthreads();

    // ---- phase 2: MFMA. wave wv -> cols wv*16..+15 of the 16-row tile.
    int lane = tid & 63, wv = tid >> 6, m = lane & 15, quad = lane >> 4;
    f32x4 acc = (f32x4){0.f, 0.f, 0.f, 0.f};
#pragma unroll
    for (int kt = 0; kt < 4; kt++) {
        half8 af = *(const half8*)&Hs[m * AS + kt * 32 + quad * 8];
        half8 bf = *(const half8*)&Ws[(wv * 16 + m) * AS + kt * 32 + quad * 8];
        acc = __builtin_amdgcn_mfma_f32_16x16x32_f16(af, bf, acc, 0, 0, 0);
    }
#pragma unroll
    for (int r = 0; r < 4; r++) {
        int gn = node0 + quad * 4 + r;
        xw2[(size_t)gn * 64 + wv * 16 + m] = (_Float16)(acc[r] * dis[gn]);
    }
}

// ------------------------------------------------- agg F=64 fused with mean-pool
__global__ __launch_bounds__(256) void k_agg_pool(const _Float16* __restrict__ xw,
                                                  const float* __restrict__ dis,
                                                  const unsigned* __restrict__ edata,
                                                  const int* __restrict__ rs,
                                                  const float* __restrict__ bias,
                                                  const int* __restrict__ batch,
                                                  float* __restrict__ g,
                                                  int* __restrict__ gcnt, int N) {
    constexpr int F = 64;
    __shared__ float T[16][F + 4];
    __shared__ int sb[16];
    int tid  = threadIdx.x;
    int base = blockIdx.x * 16;
    int nl   = tid >> 4;
    int node = base + nl;
    int j4   = (tid & 15) * 4;
    if (tid < 16) sb[tid] = batch[base + tid];

    float dv = dis[node];
    float4 self = ldh4(xw + (size_t)node * F + j4);
    float4 bv   = ld4(bias + j4);
    float4 a0 = make_float4(self.x * dv + bv.x, self.y * dv + bv.y,
                            self.z * dv + bv.z, self.w * dv + bv.w);
    float4 a1 = make_float4(0.f, 0.f, 0.f, 0.f);
    float4 a2 = a1, a3 = a1;
    int s = rs[node], e = rs[node + 1];
    int j = s;
    for (; j + 4 <= e; j += 4) {
        unsigned q0 = edata[j + 0], q1 = edata[j + 1], q2 = edata[j + 2], q3 = edata[j + 3];
        float4 v0 = ldh4(xw + (size_t)(q0 >> 16) * F + j4);
        float4 v1 = ldh4(xw + (size_t)(q1 >> 16) * F + j4);
        float4 v2 = ldh4(xw + (size_t)(q2 >> 16) * F + j4);
        float4 v3 = ldh4(xw + (size_t)(q3 >> 16) * F + j4);
        float n0 = unpack_w(q0), n1 = unpack_w(q1), n2 = unpack_w(q2), n3 = unpack_w(q3);
        a0.x += n0 * v0.x; a0.y += n0 * v0.y; a0.z += n0 * v0.z; a0.w += n0 * v0.w;
        a1.x += n1 * v1.x; a1.y += n1 * v1.y; a1.z += n1 * v1.z; a1.w += n1 * v1.w;
        a2.x += n2 * v2.x; a2.y += n2 * v2.y; a2.z += n2 * v2.z; a2.w += n2 * v2.w;
        a3.x += n3 * v3.x; a3.y += n3 * v3.y; a3.z += n3 * v3.z; a3.w += n3 * v3.w;
    }
    for (; j < e; j++) {
        unsigned q = edata[j];
        float nm = unpack_w(q);
        float4 v = ldh4(xw + (size_t)(q >> 16) * F + j4);
        a0.x += nm * v.x; a0.y += nm * v.y; a0.z += nm * v.z; a0.w += nm * v.w;
    }
    T[nl][j4 + 0] = fmaxf((a0.x + a1.x) + (a2.x + a3.x), 0.f);
    T[nl][j4 + 1] = fmaxf((a0.y + a1.y) + (a2.y + a3.y), 0.f);
    T[nl][j4 + 2] = fmaxf((a0.z + a1.z) + (a2.z + a3.z), 0.f);
    T[nl][j4 + 3] = fmaxf((a0.w + a1.w) + (a2.w + a3.w), 0.f);
    __syncthreads();
    if (tid < 64) {
        int f = tid;
        float run = 0.f;
        int cur = -1, cnt = 0;
        for (int k = 0; k < 16; k++) {
            int b = sb[k];
            if (b != cur) {
                if (cur >= 0) {
                    atomicAdd(&g[cur * 64 + f], run);
                    if (f == 0) atomicAdd(&gcnt[cur], cnt);
                }
                cur = b; run = 0.f; cnt = 0;
            }
            run += T[k][f];
            cnt++;
        }
        atomicAdd(&g[cur * 64 + f], run);
        if (f == 0) atomicAdd(&gcnt[cur], cnt);
    }
}

// ------------------------------------------------- FC: out[NG,FLAT] = (g/cnt) @ Wfc + bfc
__global__ __launch_bounds__(256) void k_fc(const float* __restrict__ g,
                                            const int* __restrict__ gcnt,
                                            const float* __restrict__ Wfc,
                                            const float* __restrict__ bfc,
                                            float* __restrict__ out) {
    __shared__ float gs[64];
    int i = blockIdx.y;
    int j = blockIdx.x * blockDim.x + threadIdx.x;
    if (threadIdx.x < 64) {
        float c = (float)gcnt[i];
        gs[threadIdx.x] = g[i * 64 + threadIdx.x] / fmaxf(c, 1.0f);
    }
    __syncthreads();
    if (j >= FLAT) return;
    float acc = bfc[j];
#pragma unroll 8
    for (int k = 0; k < 64; k++) acc += gs[k] * Wfc[k * FLAT + j];
    out[(size_t)i * FLAT + j] = acc;
}

// ================================================================ launcher
extern "C" void kernel_launch(void* const* d_in, const int* in_sizes, int n_in,
                              void* d_out, int out_size, void* d_ws, size_t ws_size,
                              hipStream_t stream) {
    const float* x    = (const float*)d_in[0];
    const int*   ei   = (const int*)d_in[1];
    const float* ew   = (const float*)d_in[2];
    const int*   batch= (const int*)d_in[3];
    const float* W1   = (const float*)d_in[4];
    const float* b1   = (const float*)d_in[5];
    const float* W2   = (const float*)d_in[6];
    const float* b2   = (const float*)d_in[7];
    const float* Wfc  = (const float*)d_in[8];
    const float* bfc  = (const float*)d_in[9];
    float* out = (float*)d_out;

    const int N = in_sizes[0] / K128;   // 40000
    const int E = in_sizes[2];          // 640000
    const int* row = ei;
    const int* col = ei + E;
    const int nbk = (N + BKB - 1) / BKB;   // 157 buckets
    const int neb = (E + 1023) / 1024;     // edge-chunk blocks

    // ---- workspace carve (256B aligned)
    char* p = (char*)d_ws;
    auto alloc = [&](size_t bytes) -> void* {
        void* r = (void*)p;
        p += (bytes + 255) & ~(size_t)255;
        return r;
    };
    float*     dis   = (float*)    alloc((size_t)N * 4);
    int*       rs    = (int*)      alloc((size_t)(N + 1) * 4);
    uint2*     bk    = (uint2*)    alloc((size_t)E * 8);
    unsigned*  edata = (unsigned*) alloc((size_t)E * 4);
    _Float16*  xw1   = (_Float16*) alloc((size_t)N * 128 * 2);
    _Float16*  xw2   = (_Float16*) alloc((size_t)N * 64 * 2);
    _Float16*  Wt1   = (_Float16*) alloc((size_t)128 * 128 * 2);
    _Float16*  Wt2   = (_Float16*) alloc((size_t)64 * 128 * 2);
    float*     g     = (float*)    alloc(64 * 64 * 4);
    int*       gcnt  = (int*)      alloc(64 * 4);
    int*       bhist = (int*)      alloc(BKB * 4);
    int*       bcur  = (int*)      alloc(BKB * 4);

    // ---- 8 dispatches total
    k_init     <<<96,  256, 0, stream>>>(bhist, bcur, g, gcnt, W1, W2, Wt1, Wt2);
    k_bhist    <<<neb, 256, 0, stream>>>(col, bhist, E, nbk);
    k_bucket   <<<neb, 256, 0, stream>>>(row, col, ew, bhist, bcur, bk, E, nbk);
    k_colsedata<<<nbk, 256, 0, stream>>>(bk, bhist, dis, rs, edata, N, E, nbk);

    k_gemm1    <<<N / 64, 256, 0, stream>>>(x, Wt1, dis, xw1, N);
    k_agg_gemm <<<N / 16, 256, 0, stream>>>(xw1, dis, edata, rs, b1, Wt2, xw2, N);
    k_agg_pool <<<N / 16, 256, 0, stream>>>(xw2, dis, edata, rs, b2, batch, g, gcnt, N);

    dim3 fcg((FLAT + 255) / 256, NG);
    k_fc<<<fcg, 256, 0, stream>>>(g, gcnt, Wfc, bfc, out);
}